// Round 5
// baseline (688.638 us; speedup 1.0000x reference)
//
#include <hip/hip_runtime.h>
#include <hip/hip_bf16.h>

// Problem constants (B=2,T=64,N=64,D_IN=512,HID=256,L=2,H=4,C=64)
#define BT_G   128
#define NND    64
#define D_IN_  512
#define HID_   256
#define NH     4
#define NCH    64
#define NROWS  8192
#define LN_EPS_    1e-5f
#define NBLK   512

typedef __hip_bfloat16 bf16;
typedef __attribute__((ext_vector_type(8))) short short8;   // 8 bf16 = 4 VGPRs
typedef __attribute__((ext_vector_type(4))) float float4v;  // MFMA C/D

// ---------------------------------------------------------------------------
// Monotonic grid barrier. Counters are __device__ globals (zero at module
// load, NEVER reset — each launch's cohort waits for its own +512 window), so
// workspace poisoning can't corrupt them and no pre-zeroing race exists.
// Fences only at the synchronized barrier point (round-3 lesson: staggered
// per-block fences destroy L2 for running blocks; synchronized ones don't).
__device__ __align__(64) int g_bar[16 * 16];

__device__ __forceinline__ void grid_barrier(int p) {
    __syncthreads();
    if (threadIdx.x == 0) {
        __threadfence();   // release: this block's writes → device scope
        const int old = __hip_atomic_fetch_add(&g_bar[p * 16], 1,
                                               __ATOMIC_RELEASE,
                                               __HIP_MEMORY_SCOPE_AGENT);
        const int goal = ((old >> 9) << 9) + NBLK;   // this launch's cohort
        while (__hip_atomic_load(&g_bar[p * 16], __ATOMIC_ACQUIRE,
                                 __HIP_MEMORY_SCOPE_AGENT) < goal)
            __builtin_amdgcn_s_sleep(16);
        __threadfence();   // acquire: drop stale cached lines
    }
    __syncthreads();
}

// ---------------------------------------------------------------------------
// Shared-memory arena: one union, max member 73216 B -> 2 blocks/CU.
union Arena {
    struct { float t[32][33]; } tr;                       // transpose tile
    struct { int flags[4]; } mk;                          // mask-layout probe
    struct { bf16 As[64 * 72]; bf16 Bs[64 * 72]; } gi;    // gemm_in
    struct { bf16 As[128 * 72]; bf16 Bs[64 * 72]; } gm;   // gemm_mfma
    struct {
        float xls[64][68], xlsT[64][68], xrsT[64][68], esT[64][68];
        float av[64], P[64], Q[64], mxf[64], inv[64];
        float pmax[4][64], psum[4][64];
        int   ms[64];
    } at;                                                 // attention
};

// ---------------------------------------------------------------------------
// The whole pipeline in one persistent kernel. 512 blocks x 256 threads,
// __launch_bounds__(256,2) => 2 blocks/CU (LDS 73.2KB x2 = 146KB < 160KB),
// all 512 co-resident. 7 grid barriers replace 7 dispatch boundaries.
// Stage bodies are the verified baseline kernels, remapped onto 512 blocks.
__global__ __launch_bounds__(256, 2) void mega_kernel(
    const float* x, const unsigned* mw, const float* W_in, const float* b_in,
    const float* Wl, const float* bl, const float* Wr, const float* br,
    const float* att, const float* ob, const float* lns, const float* lnb,
    float* out, int* mcan, float* h, float* xlb, float* xrb,
    bf16* hxb, bf16* WTin, bf16* WlrT)
{
    __shared__ Arena ar;
    const int tid = threadIdx.x;
    const int bid = blockIdx.x;

    // ================= S0: weight transposes + mask canonicalize ==========
    if (bid < 384) {
        int z, xb, yb;
        if (bid < 128) { z = 0; xb = bid & 7; yb = bid >> 3; }
        else { const int q = bid - 128; z = 1 + (q >> 6);
               const int s = q & 63; xb = s & 7; yb = s >> 3; }
        const float* src; bf16* dst; int K;
        if (z == 0)      { src = W_in;                 dst = WTin;                         K = 512; }
        else if (z <= 2) { src = Wl + (z - 1) * 65536; dst = WlrT + (z - 1) * 131072;      K = 256; }
        else             { src = Wr + (z - 3) * 65536; dst = WlrT + (z - 3) * 131072 + 65536; K = 256; }
        const int n0 = xb * 32, k0 = yb * 32;
        const int tx = tid & 31, ty = tid >> 5;
        #pragma unroll
        for (int i = 0; i < 4; ++i)
            ar.tr.t[ty + 8 * i][tx] = src[(size_t)(k0 + ty + 8 * i) * 256 + n0 + tx];
        __syncthreads();
        #pragma unroll
        for (int i = 0; i < 4; ++i)
            dst[(size_t)(n0 + ty + 8 * i) * K + k0 + tx] =
                __float2bfloat16(ar.tr.t[tx][ty + 8 * i]);
    } else if (bid == 384) {
        int* fl = ar.mk.flags;
        if (tid == 0) { fl[0] = 1; fl[1] = 1; fl[2] = 1; fl[3] = 1; }
        __syncthreads();
        int aI = 1, aF = 1, aB = 1, aC = 1;
        for (int i = tid; i < 2048; i += 256) {   // 8 KB probe — safe all layouts
            const unsigned w2 = mw[i];
            aI &= (w2 <= 1u);
            aF &= (w2 == 0u || w2 == 0x3F800000u);
            const unsigned lo = w2 & 0xFFFFu, hi = w2 >> 16;
            aB &= ((lo == 0u || lo == 0x3F80u) && (hi == 0u || hi == 0x3F80u));
            aC &= (((w2 | (w2 >> 8) | (w2 >> 16) | (w2 >> 24)) & 0xFEu) == 0u);
        }
        if (!aI) atomicAnd(&fl[0], 0);
        if (!aF) atomicAnd(&fl[1], 0);
        if (!aB) atomicAnd(&fl[2], 0);
        if (!aC) atomicAnd(&fl[3], 0);
        __syncthreads();
        const int layout = (fl[0] || fl[1]) ? 0 : (fl[2] ? 2 : (fl[3] ? 3 : 0));
        for (int i = tid; i < NROWS; i += 256) {
            int v;
            if (layout == 2)      v = (((const unsigned short*)mw)[i] != 0);
            else if (layout == 3) v = (((const unsigned char*)mw)[i] != 0);
            else                  v = (mw[i] != 0u);
            mcan[i] = v;
        }
    }
    grid_barrier(0);

    // ================= S1: input GEMM h0 = x @ W_in^T + b =================
    {
        bf16* As = ar.gi.As;
        bf16* Bs = ar.gi.Bs;
        const int wave = tid >> 6, lane = tid & 63;
        const int quad = lane >> 4, l16 = lane & 15;
        const int m0 = (bid >> 2) * 64, n0 = (bid & 3) * 64;
        const int wm = (wave & 1) * 32, wn = (wave >> 1) * 32;
        float4v acc[2][2] = {};
        const int r  = tid >> 2;
        const int cq = (tid & 3) * 16;
        for (int k0 = 0; k0 < D_IN_; k0 += 64) {
            const float* sa = x + (size_t)(m0 + r) * D_IN_ + k0 + cq;
            const float4 f0 = *(const float4*)(sa);
            const float4 f1 = *(const float4*)(sa + 4);
            const float4 f2 = *(const float4*)(sa + 8);
            const float4 f3 = *(const float4*)(sa + 12);
            const bf16* sb = WTin + (size_t)(n0 + r) * D_IN_ + k0 + cq;
            const float4 b0 = *(const float4*)(sb);
            const float4 b1 = *(const float4*)(sb + 8);
            union { bf16 hh[16]; float4 v[2]; } u;
            u.hh[0]=__float2bfloat16(f0.x); u.hh[1]=__float2bfloat16(f0.y);
            u.hh[2]=__float2bfloat16(f0.z); u.hh[3]=__float2bfloat16(f0.w);
            u.hh[4]=__float2bfloat16(f1.x); u.hh[5]=__float2bfloat16(f1.y);
            u.hh[6]=__float2bfloat16(f1.z); u.hh[7]=__float2bfloat16(f1.w);
            u.hh[8]=__float2bfloat16(f2.x); u.hh[9]=__float2bfloat16(f2.y);
            u.hh[10]=__float2bfloat16(f2.z); u.hh[11]=__float2bfloat16(f2.w);
            u.hh[12]=__float2bfloat16(f3.x); u.hh[13]=__float2bfloat16(f3.y);
            u.hh[14]=__float2bfloat16(f3.z); u.hh[15]=__float2bfloat16(f3.w);
            __syncthreads();
            *(float4*)(&As[r * 72 + cq])     = u.v[0];
            *(float4*)(&As[r * 72 + cq + 8]) = u.v[1];
            *(float4*)(&Bs[r * 72 + cq])     = b0;
            *(float4*)(&Bs[r * 72 + cq + 8]) = b1;
            __syncthreads();
            #pragma unroll
            for (int kk = 0; kk < 64; kk += 32) {
                short8 af[2], bf2[2];
                #pragma unroll
                for (int mi = 0; mi < 2; ++mi)
                    af[mi] = *(const short8*)(&As[(wm + mi * 16 + l16) * 72 + kk + quad * 8]);
                #pragma unroll
                for (int ni = 0; ni < 2; ++ni)
                    bf2[ni] = *(const short8*)(&Bs[(wn + ni * 16 + l16) * 72 + kk + quad * 8]);
                #pragma unroll
                for (int mi = 0; mi < 2; ++mi)
                    #pragma unroll
                    for (int ni = 0; ni < 2; ++ni)
                        acc[mi][ni] = __builtin_amdgcn_mfma_f32_16x16x32_bf16(
                            af[mi], bf2[ni], acc[mi][ni], 0, 0, 0);
            }
        }
        #pragma unroll
        for (int ni = 0; ni < 2; ++ni) {
            const int col = n0 + wn + ni * 16 + l16;
            const float bv = b_in[col];
            #pragma unroll
            for (int mi = 0; mi < 2; ++mi)
                #pragma unroll
                for (int rr = 0; rr < 4; ++rr) {
                    const int row = m0 + wm + mi * 16 + quad * 4 + rr;
                    const float v = acc[mi][ni][rr] + bv;
                    out[(size_t)row * HID_ + col] = v;
                    hxb[(size_t)row * HID_ + col] = __float2bfloat16(v);
                }
        }
    }
    grid_barrier(1);

    // ================= per-layer: gemm -> attn -> epilogue ================
    for (int li = 0; li < 2; ++li) {
        // ---- S2: fused xl|xr GEMM (tile 128x64, BK=64) -------------------
        {
            bf16* As = ar.gm.As;
            bf16* Bs = ar.gm.Bs;
            const bf16* BT = WlrT + (size_t)li * 512 * HID_;
            const float* bias0 = bl + li * HID_;
            const float* bias1 = br + li * HID_;
            const int wave = tid >> 6, lane = tid & 63;
            const int quad = lane >> 4, l16 = lane & 15;
            const int m0 = (bid >> 3) * 128, n0g = (bid & 7) * 64;
            const int wm = (wave & 1) * 64, wn = (wave >> 1) * 32;
            float4v acc[4][2] = {};
            const int r  = tid >> 2;
            const int cq = (tid & 3) * 16;
            for (int k0 = 0; k0 < HID_; k0 += 64) {
                const bf16* sa0 = hxb + (size_t)(m0 + r) * HID_ + k0 + cq;
                const bf16* sa1 = sa0 + (size_t)64 * HID_;
                const bf16* sb  = BT + (size_t)(n0g + r) * HID_ + k0 + cq;
                const float4 a00 = *(const float4*)(sa0);
                const float4 a01 = *(const float4*)(sa0 + 8);
                const float4 a10 = *(const float4*)(sa1);
                const float4 a11 = *(const float4*)(sa1 + 8);
                const float4 b0  = *(const float4*)(sb);
                const float4 b1  = *(const float4*)(sb + 8);
                __syncthreads();
                *(float4*)(&As[r * 72 + cq])            = a00;
                *(float4*)(&As[r * 72 + cq + 8])        = a01;
                *(float4*)(&As[(r + 64) * 72 + cq])     = a10;
                *(float4*)(&As[(r + 64) * 72 + cq + 8]) = a11;
                *(float4*)(&Bs[r * 72 + cq])            = b0;
                *(float4*)(&Bs[r * 72 + cq + 8])        = b1;
                __syncthreads();
                #pragma unroll
                for (int kk = 0; kk < 64; kk += 32) {
                    short8 af[4], bf2[2];
                    #pragma unroll
                    for (int mi = 0; mi < 4; ++mi)
                        af[mi] = *(const short8*)(&As[(wm + mi * 16 + l16) * 72 + kk + quad * 8]);
                    #pragma unroll
                    for (int ni = 0; ni < 2; ++ni)
                        bf2[ni] = *(const short8*)(&Bs[(wn + ni * 16 + l16) * 72 + kk + quad * 8]);
                    #pragma unroll
                    for (int mi = 0; mi < 4; ++mi)
                        #pragma unroll
                        for (int ni = 0; ni < 2; ++ni)
                            acc[mi][ni] = __builtin_amdgcn_mfma_f32_16x16x32_bf16(
                                af[mi], bf2[ni], acc[mi][ni], 0, 0, 0);
                }
            }
            const bool loHalf = (n0g < 256);
            float* Co = loHalf ? xlb : xrb;
            const float* bp = loHalf ? bias0 : bias1;
            const int cbase = loHalf ? n0g : (n0g - 256);
            #pragma unroll
            for (int ni = 0; ni < 2; ++ni) {
                const int col = cbase + wn + ni * 16 + l16;
                const float bv = bp[col];
                #pragma unroll
                for (int mi = 0; mi < 4; ++mi)
                    #pragma unroll
                    for (int rr = 0; rr < 4; ++rr) {
                        const int row = m0 + wm + mi * 16 + quad * 4 + rr;
                        Co[(size_t)row * 256 + col] = acc[mi][ni][rr] + bv;
                    }
            }
        }
        grid_barrier(2 + li * 3);

        // ---- S3: GATv2 attention per (graph, head), 4x4-tiled ------------
        // g aliases xr: each block reads exactly the slice it writes, reads
        // precede writes in-block, slices disjoint across blocks (verified).
        {
            auto& A = ar.at;
            const int head = bid & 3, gr = bid >> 2;
            const float* attp = att + li * NH * NCH;
            float* g = xrb;
            const int ti = tid >> 4, tj = tid & 15;
            const int i0 = ti * 4, j0 = tj * 4;
            const float* xlg = xlb + (size_t)gr * NND * HID_ + head * NCH;
            const float* xrg = xrb + (size_t)gr * NND * HID_ + head * NCH;
            {
                const int r  = tid >> 2;
                const int c0 = (tid & 3) * 16;
                float a[4][4], b[4][4];
                #pragma unroll
                for (int k = 0; k < 4; ++k) {
                    *(float4*)a[k] = *(const float4*)(xlg + r * HID_ + c0 + 4 * k);
                    *(float4*)b[k] = *(const float4*)(xrg + r * HID_ + c0 + 4 * k);
                }
                #pragma unroll
                for (int k = 0; k < 4; ++k)
                    *(float4*)&A.xls[r][c0 + 4 * k] = *(float4*)a[k];
                #pragma unroll
                for (int k = 0; k < 4; ++k)
                    #pragma unroll
                    for (int w = 0; w < 4; ++w) {
                        A.xlsT[c0 + 4 * k + w][r] = a[k][w];
                        A.xrsT[c0 + 4 * k + w][r] = b[k][w];
                    }
            }
            if (tid < 64) {
                A.av[tid] = attp[head * NCH + tid];
                A.ms[tid] = mcan[gr * NND + tid];
            }
            __syncthreads();

            float aa[4][4] = {};
            for (int c = 0; c < 64; ++c) {
                float xr4[4], xl4[4];
                *(float4*)xr4 = *(const float4*)&A.xrsT[c][i0];
                *(float4*)xl4 = *(const float4*)&A.xlsT[c][j0];
                const float a = A.av[c];
                #pragma unroll
                for (int y = 0; y < 4; ++y)
                    #pragma unroll
                    for (int xx = 0; xx < 4; ++xx)
                        aa[y][xx] = fmaf(a, fabsf(xr4[y] + xl4[xx]), aa[y][xx]);
            }
            if (tid < 64) {
                float s = 0.f;
                for (int c = 0; c < 64; ++c) s = fmaf(A.av[c], A.xrsT[c][tid], s);
                A.P[tid] = s;
            } else if (tid < 128) {
                const int j = tid - 64;
                float s = 0.f;
                for (int c = 0; c < 64; ++c) s = fmaf(A.av[c], A.xlsT[c][j], s);
                A.Q[j] = s;
            }
            __syncthreads();

            {
                float Pv[4], Qv[4]; int mi4[4], mj4[4];
                #pragma unroll
                for (int y = 0; y < 4; ++y) { Pv[y] = A.P[i0 + y]; mi4[y] = A.ms[i0 + y]; }
                #pragma unroll
                for (int xx = 0; xx < 4; ++xx) { Qv[xx] = A.Q[j0 + xx]; mj4[xx] = A.ms[j0 + xx]; }
                #pragma unroll
                for (int xx = 0; xx < 4; ++xx) {
                    float col[4];
                    #pragma unroll
                    for (int y = 0; y < 4; ++y) {
                        float e = fmaf(0.4f, aa[y][xx], 0.6f * (Pv[y] + Qv[xx]));
                        const bool allowed = (mi4[y] && mj4[xx]) || (i0 + y == j0 + xx);
                        col[y] = allowed ? e : -1e9f;
                    }
                    *(float4*)&A.esT[j0 + xx][i0] = *(float4*)col;
                }
            }
            __syncthreads();

            {
                const int si = tid & 63, q = tid >> 6;
                float mx = -1e30f;
                #pragma unroll
                for (int k = 0; k < 16; ++k) mx = fmaxf(mx, A.esT[16 * q + k][si]);
                A.pmax[q][si] = mx;
            }
            __syncthreads();
            if (tid < 64)
                A.mxf[tid] = fmaxf(fmaxf(A.pmax[0][tid], A.pmax[1][tid]),
                                   fmaxf(A.pmax[2][tid], A.pmax[3][tid]));
            __syncthreads();
            {
                const int si = tid & 63, q = tid >> 6;
                const float mx = A.mxf[si];
                float s = 0.f;
                #pragma unroll
                for (int k = 0; k < 16; ++k) {
                    const float ev = __expf(A.esT[16 * q + k][si] - mx);
                    A.esT[16 * q + k][si] = ev;
                    s += ev;
                }
                A.psum[q][si] = s;
            }
            __syncthreads();
            if (tid < 64)
                A.inv[tid] = 1.f / (A.psum[0][tid] + A.psum[1][tid] +
                                    A.psum[2][tid] + A.psum[3][tid]);
            __syncthreads();

            {
                const int c0 = j0;
                float oa[4][4] = {};
                for (int j = 0; j < 64; ++j) {
                    float al[4], xv[4];
                    *(float4*)al = *(const float4*)&A.esT[j][i0];
                    *(float4*)xv = *(const float4*)&A.xls[j][c0];
                    #pragma unroll
                    for (int y = 0; y < 4; ++y)
                        #pragma unroll
                        for (int xx = 0; xx < 4; ++xx)
                            oa[y][xx] = fmaf(al[y], xv[xx], oa[y][xx]);
                }
                #pragma unroll
                for (int y = 0; y < 4; ++y) {
                    const float iv = A.inv[i0 + y];
                    float o[4];
                    #pragma unroll
                    for (int xx = 0; xx < 4; ++xx) o[xx] = oa[y][xx] * iv;
                    float* go = g + (size_t)(gr * NND + i0 + y) * HID_ + head * NCH + c0;
                    *(float4*)go = *(float4*)o;
                }
            }
        }
        grid_barrier(3 + li * 3);

        // ---- S4: epilogue ELU -> LN -> +res -> mask (4 row-groups/block) -
        {
            const float* gsrc = xrb;
            const float* resf = (li == 0) ? out : h;
            float* hout = (li == 0) ? h : out;
            bf16* hb = (li == 0) ? hxb : (bf16*)nullptr;
            const float* obp  = ob  + li * HID_;
            const float* lnsp = lns + li * HID_;
            const float* lnbp = lnb + li * HID_;
            const int lane = tid & 63, wv = tid >> 6;
            for (int t4 = 0; t4 < 4; ++t4) {
                const int m = (bid << 4) + (t4 << 2) + wv;
                bool doit = true;
                if (li == 1) {
                    const int gr = m >> 6;
                    const unsigned long long bal = __ballot(mcan[gr * NND + lane] != 0);
                    doit = (__popcll(bal) > 1);   // else leave h0 rows in out
                }
                if (doit) {
                    const float* grow = gsrc + (size_t)m * HID_;
                    float v[4];
                    float sum = 0.f;
                    #pragma unroll
                    for (int q = 0; q < 4; ++q) {
                        const int c = q * 64 + lane;
                        float xv = grow[c] + obp[c];
                        xv = xv > 0.f ? xv : (__expf(xv) - 1.f);   // ELU
                        v[q] = xv; sum += xv;
                    }
                    #pragma unroll
                    for (int off = 1; off < 64; off <<= 1) sum += __shfl_xor(sum, off);
                    const float mu = sum * (1.f / 256.f);
                    float vs = 0.f;
                    #pragma unroll
                    for (int q = 0; q < 4; ++q) { const float d = v[q] - mu; vs += d * d; }
                    #pragma unroll
                    for (int off = 1; off < 64; off <<= 1) vs += __shfl_xor(vs, off);
                    const float rstd = rsqrtf(vs * (1.f / 256.f) + LN_EPS_);
                    const int mnode = mcan[m];
                    const float* rrow = resf + (size_t)m * HID_;
                    float* ho = hout + (size_t)m * HID_;
                    #pragma unroll
                    for (int q = 0; q < 4; ++q) {
                        const int c = q * 64 + lane;
                        float y = (v[q] - mu) * rstd * lnsp[c] + lnbp[c];
                        y += rrow[c];
                        y = mnode ? y : 0.f;
                        ho[c] = y;
                        if (hb) hb[(size_t)m * HID_ + c] = __float2bfloat16(y);
                    }
                }
            }
        }
        if (li == 0) grid_barrier(4);
    }
}

// ---------------------------------------------------------------------------
extern "C" void kernel_launch(void* const* d_in, const int* in_sizes, int n_in,
                              void* d_out, int out_size, void* d_ws, size_t ws_size,
                              hipStream_t stream) {
    const float* x    = (const float*)d_in[0];
    const float* W_in = (const float*)d_in[2];
    const float* b_in = (const float*)d_in[3];
    const float* Wl   = (const float*)d_in[4];
    const float* bl   = (const float*)d_in[5];
    const float* Wr   = (const float*)d_in[6];
    const float* br   = (const float*)d_in[7];
    const float* att  = (const float*)d_in[8];
    const float* ob   = (const float*)d_in[9];
    const float* lns  = (const float*)d_in[10];
    const float* lnb  = (const float*)d_in[11];
    float* out = (float*)d_out;

    // ws (~29 MB): [mcan 32K][h 8M][xlb 8M][xrb 8M][hxb 4M][WTin 256K][WlrT 512K]
    char* w = (char*)d_ws;
    int*   mcan = (int*)w;                      w += 32768;
    float* h    = (float*)w;                    w += (size_t)NROWS * HID_ * 4;
    float* xlb  = (float*)w;                    w += (size_t)NROWS * HID_ * 4;
    float* xrb  = (float*)w;                    w += (size_t)NROWS * HID_ * 4;
    bf16*  hxb  = (bf16*)w;                     w += (size_t)NROWS * HID_ * 2;
    bf16*  WTin = (bf16*)w;                     w += (size_t)D_IN_ * HID_ * 2;
    bf16*  WlrT = (bf16*)w;                     // [L][512][256]

    mega_kernel<<<NBLK, 256, 0, stream>>>(
        x, (const unsigned*)d_in[1], W_in, b_in, Wl, bl, Wr, br,
        att, ob, lns, lnb, out, mcan, h, xlb, xrb, hxb, WTin, WlrT);

    (void)in_sizes; (void)n_in; (void)out_size; (void)ws_size;
}

// Round 6
// 218.084 us; speedup vs baseline: 3.1577x; 3.1577x over previous
//
#include <hip/hip_runtime.h>
#include <hip/hip_bf16.h>

// Problem constants (B=2,T=64,N=64,D_IN=512,HID=256,L=2,H=4,C=64)
#define BT_G   128
#define NND    64
#define D_IN_  512
#define HID_   256
#define NH     4
#define NCH    64
#define NROWS  8192
#define LN_EPS_    1e-5f

typedef __hip_bfloat16 bf16;
typedef __attribute__((ext_vector_type(8))) short short8;   // 8 bf16 = 4 VGPRs
typedef __attribute__((ext_vector_type(4))) float float4v;  // MFMA C/D

// ---------------------------------------------------------------------------
// Dispatch 1 (heterogeneous, 769 blocks):
//   bid <  512 : input GEMM h0 = x @ W_in^T + b_in (64x64 tile, BK=64),
//                transposing W_in tiles in-staging (no WTin buffer).
//   bid <  768 : Wl/Wr -> WlrT transposes (consumed by later dispatches).
//   bid == 768 : mask canonicalize -> mcan.
union PrepArena {
    float t[32][33];
    struct { bf16 As[64 * 72]; bf16 Bs[64 * 72]; } g;
    int flags[4];
};

__global__ __launch_bounds__(256) void prep_gemm_in_kernel(
    const float* __restrict__ x, const unsigned* __restrict__ mw,
    const float* __restrict__ W_in, const float* __restrict__ b_in,
    const float* __restrict__ Wl, const float* __restrict__ Wr,
    float* __restrict__ Cf, bf16* __restrict__ Cb16,
    bf16* __restrict__ WlrT, int* __restrict__ mout)
{
    __shared__ PrepArena ar;
    const int tid = threadIdx.x;
    const int bid = blockIdx.x;

    if (bid < 512) {
        bf16* As = ar.g.As;
        bf16* Bs = ar.g.Bs;
        const int wave = tid >> 6, lane = tid & 63;
        const int quad = lane >> 4, l16 = lane & 15;
        const int m0 = (bid >> 2) * 64, n0 = (bid & 3) * 64;
        const int wm = (wave & 1) * 32, wn = (wave >> 1) * 32;
        float4v acc[2][2] = {};
        const int r  = tid >> 2;
        const int cq = (tid & 3) * 16;
        for (int k0 = 0; k0 < D_IN_; k0 += 64) {
            const float* sa = x + (size_t)(m0 + r) * D_IN_ + k0 + cq;
            const float4 f0 = *(const float4*)(sa);
            const float4 f1 = *(const float4*)(sa + 4);
            const float4 f2 = *(const float4*)(sa + 8);
            const float4 f3 = *(const float4*)(sa + 12);
            // B-tile: Bs[n][k] = bf16(W_in[k0+k][n0+n]); read rows, scatter.
            const float* sw = W_in + (size_t)(k0 + r) * HID_ + n0 + cq;
            float wv[16];
            *(float4*)(wv)      = *(const float4*)(sw);
            *(float4*)(wv + 4)  = *(const float4*)(sw + 4);
            *(float4*)(wv + 8)  = *(const float4*)(sw + 8);
            *(float4*)(wv + 12) = *(const float4*)(sw + 12);
            union { bf16 hh[16]; float4 v[2]; } u;
            u.hh[0]=__float2bfloat16(f0.x); u.hh[1]=__float2bfloat16(f0.y);
            u.hh[2]=__float2bfloat16(f0.z); u.hh[3]=__float2bfloat16(f0.w);
            u.hh[4]=__float2bfloat16(f1.x); u.hh[5]=__float2bfloat16(f1.y);
            u.hh[6]=__float2bfloat16(f1.z); u.hh[7]=__float2bfloat16(f1.w);
            u.hh[8]=__float2bfloat16(f2.x); u.hh[9]=__float2bfloat16(f2.y);
            u.hh[10]=__float2bfloat16(f2.z); u.hh[11]=__float2bfloat16(f2.w);
            u.hh[12]=__float2bfloat16(f3.x); u.hh[13]=__float2bfloat16(f3.y);
            u.hh[14]=__float2bfloat16(f3.z); u.hh[15]=__float2bfloat16(f3.w);
            __syncthreads();
            *(float4*)(&As[r * 72 + cq])     = u.v[0];
            *(float4*)(&As[r * 72 + cq + 8]) = u.v[1];
            #pragma unroll
            for (int j = 0; j < 16; ++j)
                Bs[(cq + j) * 72 + r] = __float2bfloat16(wv[j]);
            __syncthreads();
            #pragma unroll
            for (int kk = 0; kk < 64; kk += 32) {
                short8 af[2], bf2[2];
                #pragma unroll
                for (int mi = 0; mi < 2; ++mi)
                    af[mi] = *(const short8*)(&As[(wm + mi * 16 + l16) * 72 + kk + quad * 8]);
                #pragma unroll
                for (int ni = 0; ni < 2; ++ni)
                    bf2[ni] = *(const short8*)(&Bs[(wn + ni * 16 + l16) * 72 + kk + quad * 8]);
                #pragma unroll
                for (int mi = 0; mi < 2; ++mi)
                    #pragma unroll
                    for (int ni = 0; ni < 2; ++ni)
                        acc[mi][ni] = __builtin_amdgcn_mfma_f32_16x16x32_bf16(
                            af[mi], bf2[ni], acc[mi][ni], 0, 0, 0);
            }
        }
        #pragma unroll
        for (int ni = 0; ni < 2; ++ni) {
            const int col = n0 + wn + ni * 16 + l16;
            const float bv = b_in[col];
            #pragma unroll
            for (int mi = 0; mi < 2; ++mi)
                #pragma unroll
                for (int rr = 0; rr < 4; ++rr) {
                    const int row = m0 + wm + mi * 16 + quad * 4 + rr;
                    const float v = acc[mi][ni][rr] + bv;
                    Cf[(size_t)row * HID_ + col] = v;
                    Cb16[(size_t)row * HID_ + col] = __float2bfloat16(v);
                }
        }
    } else if (bid < 768) {
        const int q = bid - 512;
        const int z4 = q >> 6;                 // 0,1: Wl li ; 2,3: Wr li
        const int s = q & 63;
        const int n0 = (s & 7) * 32, k0 = (s >> 3) * 32;
        const float* src = (z4 < 2) ? (Wl + z4 * 65536) : (Wr + (z4 - 2) * 65536);
        bf16* dst = WlrT + ((z4 < 2) ? (size_t)z4 * 131072
                                     : (size_t)(z4 - 2) * 131072 + 65536);
        const int tx = tid & 31, ty = tid >> 5;
        #pragma unroll
        for (int i = 0; i < 4; ++i)
            ar.t[ty + 8 * i][tx] = src[(size_t)(k0 + ty + 8 * i) * 256 + n0 + tx];
        __syncthreads();
        #pragma unroll
        for (int i = 0; i < 4; ++i)
            dst[(size_t)(n0 + ty + 8 * i) * 256 + k0 + tx] =
                __float2bfloat16(ar.t[tx][ty + 8 * i]);
    } else {
        int* fl = ar.flags;
        if (tid == 0) { fl[0] = 1; fl[1] = 1; fl[2] = 1; fl[3] = 1; }
        __syncthreads();
        int aI = 1, aF = 1, aB = 1, aC = 1;
        for (int i = tid; i < 2048; i += 256) {   // 8 KB probe — safe all layouts
            const unsigned w2 = mw[i];
            aI &= (w2 <= 1u);
            aF &= (w2 == 0u || w2 == 0x3F800000u);
            const unsigned lo = w2 & 0xFFFFu, hi = w2 >> 16;
            aB &= ((lo == 0u || lo == 0x3F80u) && (hi == 0u || hi == 0x3F80u));
            aC &= (((w2 | (w2 >> 8) | (w2 >> 16) | (w2 >> 24)) & 0xFEu) == 0u);
        }
        if (!aI) atomicAnd(&fl[0], 0);
        if (!aF) atomicAnd(&fl[1], 0);
        if (!aB) atomicAnd(&fl[2], 0);
        if (!aC) atomicAnd(&fl[3], 0);
        __syncthreads();
        const int layout = (fl[0] || fl[1]) ? 0 : (fl[2] ? 2 : (fl[3] ? 3 : 0));
        for (int i = tid; i < NROWS; i += 256) {
            int v;
            if (layout == 2)      v = (((const unsigned short*)mw)[i] != 0);
            else if (layout == 3) v = (((const unsigned char*)mw)[i] != 0);
            else                  v = (mw[i] != 0u);
            mout[i] = v;
        }
    }
}

// ---------------------------------------------------------------------------
// Fused xl|xr GEMM: C[M][512] = A[M][256](bf16) @ BT[512][256]^T + bias.
// Tile 128x64, BK=64; 4 waves 2x2, wave = 64x32 via 4x2 MFMA.
__global__ __launch_bounds__(256) void gemm_mfma_kernel(
    const bf16* __restrict__ A, const bf16* __restrict__ BT,
    const float* __restrict__ bias0, const float* __restrict__ bias1,
    float* __restrict__ Ca, float* __restrict__ Cbf, int M, int K)
{
    __shared__ bf16 As[128 * 72];
    __shared__ bf16 Bs[64 * 72];
    const int tid  = threadIdx.x;
    const int wave = tid >> 6, lane = tid & 63;
    const int quad = lane >> 4, l16 = lane & 15;
    const int m0 = blockIdx.y * 128, n0g = blockIdx.x * 64;
    const int wm = (wave & 1) * 64, wn = (wave >> 1) * 32;
    float4v acc[4][2] = {};
    const int r  = tid >> 2;
    const int cq = (tid & 3) * 16;

    for (int k0 = 0; k0 < K; k0 += 64) {
        const bf16* sa0 = A  + (size_t)(m0 + r) * K + k0 + cq;
        const bf16* sa1 = sa0 + (size_t)64 * K;
        const bf16* sb  = BT + (size_t)(n0g + r) * K + k0 + cq;
        const float4 a00 = *(const float4*)(sa0);
        const float4 a01 = *(const float4*)(sa0 + 8);
        const float4 a10 = *(const float4*)(sa1);
        const float4 a11 = *(const float4*)(sa1 + 8);
        const float4 b0  = *(const float4*)(sb);
        const float4 b1  = *(const float4*)(sb + 8);
        __syncthreads();
        *(float4*)(&As[r * 72 + cq])            = a00;
        *(float4*)(&As[r * 72 + cq + 8])        = a01;
        *(float4*)(&As[(r + 64) * 72 + cq])     = a10;
        *(float4*)(&As[(r + 64) * 72 + cq + 8]) = a11;
        *(float4*)(&Bs[r * 72 + cq])            = b0;
        *(float4*)(&Bs[r * 72 + cq + 8])        = b1;
        __syncthreads();
        #pragma unroll
        for (int kk = 0; kk < 64; kk += 32) {
            short8 af[4], bf2[2];
            #pragma unroll
            for (int mi = 0; mi < 4; ++mi)
                af[mi] = *(const short8*)(&As[(wm + mi * 16 + l16) * 72 + kk + quad * 8]);
            #pragma unroll
            for (int ni = 0; ni < 2; ++ni)
                bf2[ni] = *(const short8*)(&Bs[(wn + ni * 16 + l16) * 72 + kk + quad * 8]);
            #pragma unroll
            for (int mi = 0; mi < 4; ++mi)
                #pragma unroll
                for (int ni = 0; ni < 2; ++ni)
                    acc[mi][ni] = __builtin_amdgcn_mfma_f32_16x16x32_bf16(
                        af[mi], bf2[ni], acc[mi][ni], 0, 0, 0);
        }
    }
    const bool loHalf = (n0g < 256);
    float* Co = loHalf ? Ca : Cbf;
    const float* bp = loHalf ? bias0 : bias1;
    const int cbase = loHalf ? n0g : (n0g - 256);
    #pragma unroll
    for (int ni = 0; ni < 2; ++ni) {
        const int col = cbase + wn + ni * 16 + l16;
        const float bv = bp[col];
        #pragma unroll
        for (int mi = 0; mi < 4; ++mi)
            #pragma unroll
            for (int rr = 0; rr < 4; ++rr) {
                const int row = m0 + wm + mi * 16 + quad * 4 + rr;
                Co[(size_t)row * 256 + col] = acc[mi][ni][rr] + bv;
            }
    }
}

// ---------------------------------------------------------------------------
// Layer-1 GEMM with fused layer-0 epilogue prologue (row-local recompute):
// rows m0..m0+127: g0+ob -> ELU -> LN -> +res -> mask  => bf16 -> As (LDS,
// persistent across K loop). n0g==0 blocks also write fp32 h (residual for
// final epilogue). Arithmetic identical to epilogue_kernel (same shfl order).
// LDS 76.8 KB -> 2 blocks/CU.
__global__ __launch_bounds__(256, 2) void gemm_ep_kernel(
    const float* __restrict__ g0, const float* __restrict__ res,
    const float* __restrict__ ob0, const float* __restrict__ lns0,
    const float* __restrict__ lnb0, const int* __restrict__ msk,
    const bf16* __restrict__ BT, const float* __restrict__ bias0,
    const float* __restrict__ bias1, float* __restrict__ hres,
    float* __restrict__ Ca, float* __restrict__ Cbf)
{
    __shared__ bf16 As[128 * 264];
    __shared__ bf16 Bs[64 * 72];
    const int tid  = threadIdx.x;
    const int wave = tid >> 6, lane = tid & 63;
    const int quad = lane >> 4, l16 = lane & 15;
    const int m0 = blockIdx.y * 128, n0g = blockIdx.x * 64;
    const int wm = (wave & 1) * 64, wn = (wave >> 1) * 32;

    // ---- prologue: layer-0 epilogue for this block's 128 A-rows ----------
    for (int rr = wave; rr < 128; rr += 4) {
        const int m = m0 + rr;
        const float* grow = g0 + (size_t)m * HID_;
        float v[4];
        float sum = 0.f;
        #pragma unroll
        for (int q = 0; q < 4; ++q) {
            const int c = q * 64 + lane;
            float xv = grow[c] + ob0[c];
            xv = xv > 0.f ? xv : (__expf(xv) - 1.f);   // ELU (alpha=1)
            v[q] = xv; sum += xv;
        }
        #pragma unroll
        for (int off = 1; off < 64; off <<= 1) sum += __shfl_xor(sum, off);
        const float mu = sum * (1.f / 256.f);
        float vs = 0.f;
        #pragma unroll
        for (int q = 0; q < 4; ++q) { const float d = v[q] - mu; vs += d * d; }
        #pragma unroll
        for (int off = 1; off < 64; off <<= 1) vs += __shfl_xor(vs, off);
        const float rstd = rsqrtf(vs * (1.f / 256.f) + LN_EPS_);
        const int mnode = msk[m];
        const float* rrow = res + (size_t)m * HID_;
        #pragma unroll
        for (int q = 0; q < 4; ++q) {
            const int c = q * 64 + lane;
            float y = (v[q] - mu) * rstd * lns0[c] + lnb0[c];
            y += rrow[c];
            y = mnode ? y : 0.f;
            if (n0g == 0) hres[(size_t)m * HID_ + c] = y;
            As[rr * 264 + c] = __float2bfloat16(y);
        }
    }
    __syncthreads();

    // ---- K loop: only B restages; A persistent in LDS --------------------
    float4v acc[4][2] = {};
    const int r  = tid >> 2;
    const int cq = (tid & 3) * 16;
    for (int k0 = 0; k0 < HID_; k0 += 64) {
        const bf16* sb = BT + (size_t)(n0g + r) * HID_ + k0 + cq;
        const float4 b0 = *(const float4*)(sb);
        const float4 b1 = *(const float4*)(sb + 8);
        __syncthreads();
        *(float4*)(&Bs[r * 72 + cq])     = b0;
        *(float4*)(&Bs[r * 72 + cq + 8]) = b1;
        __syncthreads();
        #pragma unroll
        for (int kk = 0; kk < 64; kk += 32) {
            short8 af[4], bf2[2];
            #pragma unroll
            for (int mi = 0; mi < 4; ++mi)
                af[mi] = *(const short8*)(&As[(wm + mi * 16 + l16) * 264 + k0 + kk + quad * 8]);
            #pragma unroll
            for (int ni = 0; ni < 2; ++ni)
                bf2[ni] = *(const short8*)(&Bs[(wn + ni * 16 + l16) * 72 + kk + quad * 8]);
            #pragma unroll
            for (int mi = 0; mi < 4; ++mi)
                #pragma unroll
                for (int ni = 0; ni < 2; ++ni)
                    acc[mi][ni] = __builtin_amdgcn_mfma_f32_16x16x32_bf16(
                        af[mi], bf2[ni], acc[mi][ni], 0, 0, 0);
        }
    }
    const bool loHalf = (n0g < 256);
    float* Co = loHalf ? Ca : Cbf;
    const float* bp = loHalf ? bias0 : bias1;
    const int cbase = loHalf ? n0g : (n0g - 256);
    #pragma unroll
    for (int ni = 0; ni < 2; ++ni) {
        const int col = cbase + wn + ni * 16 + l16;
        const float bv = bp[col];
        #pragma unroll
        for (int mi = 0; mi < 4; ++mi)
            #pragma unroll
            for (int rr = 0; rr < 4; ++rr) {
                const int row = m0 + wm + mi * 16 + quad * 4 + rr;
                Co[(size_t)row * 256 + col] = acc[mi][ni][rr] + bv;
            }
    }
}

// ---------------------------------------------------------------------------
// GATv2 attention per (graph, head, i-half): grid (NH*2, BT_G), 1024 blocks,
// 47 KB LDS -> 3 blocks/CU (round-4 verified). esT overlays dead xlsT.
// g MAY ALIAS xr (reads precede writes in-block; slices disjoint).
__global__ __launch_bounds__(256) void attn_kernel(
    const float* xl, const float* xr, const float* att,
    const int* msk, float* g)
{
    __shared__ float xls [64][68];   // xl row-major [j][c]   (phase 3)
    __shared__ float xlsT[64][68];   // [c][j] (phase 1); esT[64][36] after
    __shared__ float xrsT[64][36];   // [c][i]  (32 i-rows)   (phase 1)
    __shared__ float av[64], P[32], Q[64], mxf[32], inv[32];
    __shared__ float pmax[8][32], psum[8][32];
    __shared__ int   ms[64];
    float (*esT)[36] = (float(*)[36])xlsT;   // overlay: xlsT dead after phase 1

    const int tid   = threadIdx.x;
    const int head  = blockIdx.x >> 1;
    const int half  = blockIdx.x & 1;
    const int gr    = blockIdx.y;
    const int ibase = half * 32;
    const int ti = tid >> 4, tj = tid & 15;   // 16x16 thread grid
    const int i0 = ti * 2, j0 = tj * 4;       // 2x4 tile (i half-range)

    const float* xlg = xl + (size_t)gr * NND * HID_ + head * NCH;
    const float* xrg = xr + ((size_t)gr * NND + ibase) * HID_ + head * NCH;

    {
        const int r  = tid >> 2;
        const int c0 = (tid & 3) * 16;
        const int r2 = tid >> 3;
        const int cb = (tid & 7) * 8;
        float a[4][4], b[2][4];
        #pragma unroll
        for (int k = 0; k < 4; ++k)
            *(float4*)a[k] = *(const float4*)(xlg + r * HID_ + c0 + 4 * k);
        *(float4*)b[0] = *(const float4*)(xrg + r2 * HID_ + cb);
        *(float4*)b[1] = *(const float4*)(xrg + r2 * HID_ + cb + 4);
        #pragma unroll
        for (int k = 0; k < 4; ++k)
            *(float4*)&xls[r][c0 + 4 * k] = *(float4*)a[k];
        #pragma unroll
        for (int k = 0; k < 4; ++k)
            #pragma unroll
            for (int w = 0; w < 4; ++w)
                xlsT[c0 + 4 * k + w][r] = a[k][w];
        #pragma unroll
        for (int k = 0; k < 2; ++k)
            #pragma unroll
            for (int w = 0; w < 4; ++w)
                xrsT[cb + 4 * k + w][r2] = b[k][w];
        if (tid < 64) {
            av[tid] = att[head * NCH + tid];
            ms[tid] = msk[gr * NND + tid];
        }
    }
    __syncthreads();

    float aa[2][4] = {};
    for (int c = 0; c < 64; ++c) {
        const float a = av[c];
        const float2 xr2 = *(const float2*)&xrsT[c][i0];
        const float4 xl4 = *(const float4*)&xlsT[c][j0];
        const float xrv[2] = {xr2.x, xr2.y};
        const float xlv[4] = {xl4.x, xl4.y, xl4.z, xl4.w};
        #pragma unroll
        for (int y = 0; y < 2; ++y)
            #pragma unroll
            for (int x = 0; x < 4; ++x)
                aa[y][x] = fmaf(a, fabsf(xrv[y] + xlv[x]), aa[y][x]);
    }
    if (tid < 32) {
        float s = 0.f;
        for (int c = 0; c < 64; ++c) s = fmaf(av[c], xrsT[c][tid], s);
        P[tid] = s;
    } else if (tid >= 64 && tid < 128) {
        const int j = tid - 64;
        float s = 0.f;
        for (int c = 0; c < 64; ++c) s = fmaf(av[c], xlsT[c][j], s);
        Q[j] = s;
    }
    __syncthreads();

    {
        float Pv[2], Qv[4]; int mi2[2], mj4[4];
        #pragma unroll
        for (int y = 0; y < 2; ++y) { Pv[y] = P[i0 + y]; mi2[y] = ms[ibase + i0 + y]; }
        #pragma unroll
        for (int x = 0; x < 4; ++x) { Qv[x] = Q[j0 + x]; mj4[x] = ms[j0 + x]; }
        #pragma unroll
        for (int x = 0; x < 4; ++x) {
            float col[2];
            #pragma unroll
            for (int y = 0; y < 2; ++y) {
                float e = fmaf(0.4f, aa[y][x], 0.6f * (Pv[y] + Qv[x]));
                const bool allowed = (mi2[y] && mj4[x]) || (ibase + i0 + y == j0 + x);
                col[y] = allowed ? e : -1e9f;
            }
            *(float2*)&esT[j0 + x][i0] = *(float2*)col;
        }
    }
    __syncthreads();

    {
        const int si = tid & 31, q = tid >> 5;
        float mx = -1e30f;
        #pragma unroll
        for (int k = 0; k < 8; ++k) mx = fmaxf(mx, esT[8 * q + k][si]);
        pmax[q][si] = mx;
    }
    __syncthreads();
    if (tid < 32) {
        float m = pmax[0][tid];
        #pragma unroll
        for (int q = 1; q < 8; ++q) m = fmaxf(m, pmax[q][tid]);
        mxf[tid] = m;
    }
    __syncthreads();
    {
        const int si = tid & 31, q = tid >> 5;
        const float mx = mxf[si];
        float s = 0.f;
        #pragma unroll
        for (int k = 0; k < 8; ++k) {
            const float ev = __expf(esT[8 * q + k][si] - mx);
            esT[8 * q + k][si] = ev;
            s += ev;
        }
        psum[q][si] = s;
    }
    __syncthreads();
    if (tid < 32) {
        float s = psum[0][tid];
        #pragma unroll
        for (int q = 1; q < 8; ++q) s += psum[q][tid];
        inv[tid] = 1.f / s;
    }
    __syncthreads();

    {
        float oa[2][4] = {};
        for (int j = 0; j < 64; ++j) {
            const float2 al = *(const float2*)&esT[j][i0];
            const float4 xv = *(const float4*)&xls[j][j0];
            const float alv[2] = {al.x, al.y};
            const float xvv[4] = {xv.x, xv.y, xv.z, xv.w};
            #pragma unroll
            for (int y = 0; y < 2; ++y)
                #pragma unroll
                for (int x = 0; x < 4; ++x)
                    oa[y][x] = fmaf(alv[y], xvv[x], oa[y][x]);
        }
        #pragma unroll
        for (int y = 0; y < 2; ++y) {
            const float iv = inv[i0 + y];
            float o[4];
            #pragma unroll
            for (int x = 0; x < 4; ++x) o[x] = oa[y][x] * iv;
            float* go = g + (size_t)(gr * NND + ibase + i0 + y) * HID_ + head * NCH + j0;
            *(float4*)go = *(float4*)o;
        }
    }
}

// ---------------------------------------------------------------------------
// Final epilogue (layer 1): g + ob -> ELU -> LN -> +res -> mask; only
// overwrite keep-graphs (#masked > 1); hout = d_out holding h0.
__global__ __launch_bounds__(256) void epilogue_kernel(
    const float* __restrict__ g, const float* res,
    const float* __restrict__ ob, const float* __restrict__ lns,
    const float* __restrict__ lnb, const int* __restrict__ msk,
    float* hout, bf16* hb, int finalSel)
{
    const int lane = threadIdx.x & 63;
    const int wave = threadIdx.x >> 6;
    const int m = blockIdx.x * 4 + wave;
    if (finalSel) {
        const int gr = m >> 6;
        const int mv = msk[gr * NND + lane];
        const unsigned long long bal = __ballot(mv != 0);
        if (__popcll(bal) <= 1) return;   // leave h0 rows in d_out
    }
    const float* grow = g + (size_t)m * HID_;
    float v[4];
    float sum = 0.f;
    #pragma unroll
    for (int q = 0; q < 4; ++q) {
        const int c = q * 64 + lane;
        float x = grow[c] + ob[c];
        x = x > 0.f ? x : (__expf(x) - 1.f);   // ELU (alpha=1)
        v[q] = x; sum += x;
    }
    #pragma unroll
    for (int off = 1; off < 64; off <<= 1) sum += __shfl_xor(sum, off);
    const float mu = sum * (1.f / 256.f);
    float vs = 0.f;
    #pragma unroll
    for (int q = 0; q < 4; ++q) { const float d = v[q] - mu; vs += d * d; }
    #pragma unroll
    for (int off = 1; off < 64; off <<= 1) vs += __shfl_xor(vs, off);
    const float rstd = rsqrtf(vs * (1.f / 256.f) + LN_EPS_);
    const int mnode = msk[m];
    const float* rrow = res + (size_t)m * HID_;
    float* ho = hout + (size_t)m * HID_;
    #pragma unroll
    for (int q = 0; q < 4; ++q) {
        const int c = q * 64 + lane;
        float y = (v[q] - mu) * rstd * lns[c] + lnb[c];
        y += rrow[c];
        y = mnode ? y : 0.f;
        ho[c] = y;
        if (hb) hb[(size_t)m * HID_ + c] = __float2bfloat16(y);
    }
}

// ---------------------------------------------------------------------------
extern "C" void kernel_launch(void* const* d_in, const int* in_sizes, int n_in,
                              void* d_out, int out_size, void* d_ws, size_t ws_size,
                              hipStream_t stream) {
    const float* x    = (const float*)d_in[0];
    const float* W_in = (const float*)d_in[2];
    const float* b_in = (const float*)d_in[3];
    const float* Wl   = (const float*)d_in[4];
    const float* bl   = (const float*)d_in[5];
    const float* Wr   = (const float*)d_in[6];
    const float* br   = (const float*)d_in[7];
    const float* att  = (const float*)d_in[8];
    const float* ob   = (const float*)d_in[9];
    const float* lns  = (const float*)d_in[10];
    const float* lnb  = (const float*)d_in[11];
    float* out = (float*)d_out;

    // ws (~37 MB): [mcan 32K][h 8M][xlb 8M][xra 8M][xrb2 8M][hxb 4M][WlrT 512K]
    char* w = (char*)d_ws;
    int*   mcan = (int*)w;                      w += 32768;
    float* h    = (float*)w;                    w += (size_t)NROWS * HID_ * 4;
    float* xlb  = (float*)w;                    w += (size_t)NROWS * HID_ * 4;
    float* xra  = (float*)w;                    w += (size_t)NROWS * HID_ * 4;
    float* xrb2 = (float*)w;                    w += (size_t)NROWS * HID_ * 4;
    bf16*  hxb  = (bf16*)w;                     w += (size_t)NROWS * HID_ * 2;
    bf16*  WlrT = (bf16*)w;                     // [L][512][256]

    // D1: input GEMM + Wl/Wr transposes + mask canon (heterogeneous blocks)
    prep_gemm_in_kernel<<<769, 256, 0, stream>>>(
        x, (const unsigned*)d_in[1], W_in, b_in, Wl, Wr, out, hxb, WlrT, mcan);

    // D2: layer-0 xl|xr GEMM
    gemm_mfma_kernel<<<dim3(512 / 64, NROWS / 128), 256, 0, stream>>>(
        hxb, WlrT, bl, br, xlb, xra, NROWS, HID_);

    // D3: layer-0 attention (g aliases xra)
    attn_kernel<<<dim3(NH * 2, BT_G), 256, 0, stream>>>(
        xlb, xra, att, mcan, xra);

    // D4: layer-0 epilogue fused into layer-1 GEMM (writes h, xlb, xrb2)
    gemm_ep_kernel<<<dim3(512 / 64, NROWS / 128), 256, 0, stream>>>(
        xra, out, ob, lns, lnb, mcan,
        WlrT + (size_t)512 * HID_, bl + HID_, br + HID_, h, xlb, xrb2);

    // D5: layer-1 attention (g aliases xrb2)
    attn_kernel<<<dim3(NH * 2, BT_G), 256, 0, stream>>>(
        xlb, xrb2, att + NH * NCH, mcan, xrb2);

    // D6: final epilogue with keep-graph select
    epilogue_kernel<<<NROWS / 4, 256, 0, stream>>>(
        xrb2, h, ob + HID_, lns + HID_, lnb + HID_, mcan,
        out, (bf16*)nullptr, 1);

    (void)in_sizes; (void)n_in; (void)out_size; (void)ws_size;
}

// Round 7
// 176.457 us; speedup vs baseline: 3.9026x; 1.2359x over previous
//
#include <hip/hip_runtime.h>
#include <hip/hip_bf16.h>

// Problem constants (B=2,T=64,N=64,D_IN=512,HID=256,L=2,H=4,C=64)
#define BT_G   128
#define NND    64
#define D_IN_  512
#define HID_   256
#define NH     4
#define NCH    64
#define NROWS  8192
#define LN_EPS_    1e-5f

typedef __hip_bfloat16 bf16;
typedef __attribute__((ext_vector_type(8))) short short8;   // 8 bf16 = 4 VGPRs
typedef __attribute__((ext_vector_type(4))) float float4v;  // MFMA C/D

// ---------------------------------------------------------------------------
// Dispatch 1 (heterogeneous, 769 blocks):
//   bid <  512 : input GEMM h0 = x @ W_in^T + b_in (64x64 tile, BK=64),
//                transposing W_in tiles in-staging (no WTin buffer).
//   bid <  768 : Wl/Wr -> WlrT transposes (consumed by later dispatches).
//   bid == 768 : mask canonicalize -> mcan.
union PrepArena {
    float t[32][33];
    struct { bf16 As[64 * 72]; bf16 Bs[64 * 72]; } g;
    int flags[4];
};

__global__ __launch_bounds__(256) void prep_gemm_in_kernel(
    const float* __restrict__ x, const unsigned* __restrict__ mw,
    const float* __restrict__ W_in, const float* __restrict__ b_in,
    const float* __restrict__ Wl, const float* __restrict__ Wr,
    float* __restrict__ Cf, bf16* __restrict__ Cb16,
    bf16* __restrict__ WlrT, int* __restrict__ mout)
{
    __shared__ PrepArena ar;
    const int tid = threadIdx.x;
    const int bid = blockIdx.x;

    if (bid < 512) {
        bf16* As = ar.g.As;
        bf16* Bs = ar.g.Bs;
        const int wave = tid >> 6, lane = tid & 63;
        const int quad = lane >> 4, l16 = lane & 15;
        const int m0 = (bid >> 2) * 64, n0 = (bid & 3) * 64;
        const int wm = (wave & 1) * 32, wn = (wave >> 1) * 32;
        float4v acc[2][2] = {};
        const int r  = tid >> 2;
        const int cq = (tid & 3) * 16;
        for (int k0 = 0; k0 < D_IN_; k0 += 64) {
            const float* sa = x + (size_t)(m0 + r) * D_IN_ + k0 + cq;
            const float4 f0 = *(const float4*)(sa);
            const float4 f1 = *(const float4*)(sa + 4);
            const float4 f2 = *(const float4*)(sa + 8);
            const float4 f3 = *(const float4*)(sa + 12);
            // B-tile: Bs[n][k] = bf16(W_in[k0+k][n0+n]); read rows, scatter.
            const float* sw = W_in + (size_t)(k0 + r) * HID_ + n0 + cq;
            float wv[16];
            *(float4*)(wv)      = *(const float4*)(sw);
            *(float4*)(wv + 4)  = *(const float4*)(sw + 4);
            *(float4*)(wv + 8)  = *(const float4*)(sw + 8);
            *(float4*)(wv + 12) = *(const float4*)(sw + 12);
            union { bf16 hh[16]; float4 v[2]; } u;
            u.hh[0]=__float2bfloat16(f0.x); u.hh[1]=__float2bfloat16(f0.y);
            u.hh[2]=__float2bfloat16(f0.z); u.hh[3]=__float2bfloat16(f0.w);
            u.hh[4]=__float2bfloat16(f1.x); u.hh[5]=__float2bfloat16(f1.y);
            u.hh[6]=__float2bfloat16(f1.z); u.hh[7]=__float2bfloat16(f1.w);
            u.hh[8]=__float2bfloat16(f2.x); u.hh[9]=__float2bfloat16(f2.y);
            u.hh[10]=__float2bfloat16(f2.z); u.hh[11]=__float2bfloat16(f2.w);
            u.hh[12]=__float2bfloat16(f3.x); u.hh[13]=__float2bfloat16(f3.y);
            u.hh[14]=__float2bfloat16(f3.z); u.hh[15]=__float2bfloat16(f3.w);
            __syncthreads();
            *(float4*)(&As[r * 72 + cq])     = u.v[0];
            *(float4*)(&As[r * 72 + cq + 8]) = u.v[1];
            #pragma unroll
            for (int j = 0; j < 16; ++j)
                Bs[(cq + j) * 72 + r] = __float2bfloat16(wv[j]);
            __syncthreads();
            #pragma unroll
            for (int kk = 0; kk < 64; kk += 32) {
                short8 af[2], bf2[2];
                #pragma unroll
                for (int mi = 0; mi < 2; ++mi)
                    af[mi] = *(const short8*)(&As[(wm + mi * 16 + l16) * 72 + kk + quad * 8]);
                #pragma unroll
                for (int ni = 0; ni < 2; ++ni)
                    bf2[ni] = *(const short8*)(&Bs[(wn + ni * 16 + l16) * 72 + kk + quad * 8]);
                #pragma unroll
                for (int mi = 0; mi < 2; ++mi)
                    #pragma unroll
                    for (int ni = 0; ni < 2; ++ni)
                        acc[mi][ni] = __builtin_amdgcn_mfma_f32_16x16x32_bf16(
                            af[mi], bf2[ni], acc[mi][ni], 0, 0, 0);
            }
        }
        #pragma unroll
        for (int ni = 0; ni < 2; ++ni) {
            const int col = n0 + wn + ni * 16 + l16;
            const float bv = b_in[col];
            #pragma unroll
            for (int mi = 0; mi < 2; ++mi)
                #pragma unroll
                for (int rr = 0; rr < 4; ++rr) {
                    const int row = m0 + wm + mi * 16 + quad * 4 + rr;
                    const float v = acc[mi][ni][rr] + bv;
                    Cf[(size_t)row * HID_ + col] = v;
                    Cb16[(size_t)row * HID_ + col] = __float2bfloat16(v);
                }
        }
    } else if (bid < 768) {
        const int q = bid - 512;
        const int z4 = q >> 6;                 // 0,1: Wl li ; 2,3: Wr li
        const int s = q & 63;
        const int n0 = (s & 7) * 32, k0 = (s >> 3) * 32;
        const float* src = (z4 < 2) ? (Wl + z4 * 65536) : (Wr + (z4 - 2) * 65536);
        bf16* dst = WlrT + ((z4 < 2) ? (size_t)z4 * 131072
                                     : (size_t)(z4 - 2) * 131072 + 65536);
        const int tx = tid & 31, ty = tid >> 5;
        #pragma unroll
        for (int i = 0; i < 4; ++i)
            ar.t[ty + 8 * i][tx] = src[(size_t)(k0 + ty + 8 * i) * 256 + n0 + tx];
        __syncthreads();
        #pragma unroll
        for (int i = 0; i < 4; ++i)
            dst[(size_t)(n0 + ty + 8 * i) * 256 + k0 + tx] =
                __float2bfloat16(ar.t[tx][ty + 8 * i]);
    } else {
        int* fl = ar.flags;
        if (tid == 0) { fl[0] = 1; fl[1] = 1; fl[2] = 1; fl[3] = 1; }
        __syncthreads();
        int aI = 1, aF = 1, aB = 1, aC = 1;
        for (int i = tid; i < 2048; i += 256) {   // 8 KB probe — safe all layouts
            const unsigned w2 = mw[i];
            aI &= (w2 <= 1u);
            aF &= (w2 == 0u || w2 == 0x3F800000u);
            const unsigned lo = w2 & 0xFFFFu, hi = w2 >> 16;
            aB &= ((lo == 0u || lo == 0x3F80u) && (hi == 0u || hi == 0x3F80u));
            aC &= (((w2 | (w2 >> 8) | (w2 >> 16) | (w2 >> 24)) & 0xFEu) == 0u);
        }
        if (!aI) atomicAnd(&fl[0], 0);
        if (!aF) atomicAnd(&fl[1], 0);
        if (!aB) atomicAnd(&fl[2], 0);
        if (!aC) atomicAnd(&fl[3], 0);
        __syncthreads();
        const int layout = (fl[0] || fl[1]) ? 0 : (fl[2] ? 2 : (fl[3] ? 3 : 0));
        for (int i = tid; i < NROWS; i += 256) {
            int v;
            if (layout == 2)      v = (((const unsigned short*)mw)[i] != 0);
            else if (layout == 3) v = (((const unsigned char*)mw)[i] != 0);
            else                  v = (mw[i] != 0u);
            mout[i] = v;
        }
    }
}

// ---------------------------------------------------------------------------
// Fused xl|xr GEMM: C[M][512] = A[M][256](bf16) @ BT[512][256]^T + bias.
// Tile 128x64, BK=64; 4 waves 2x2, wave = 64x32 via 4x2 MFMA.
__global__ __launch_bounds__(256) void gemm_mfma_kernel(
    const bf16* __restrict__ A, const bf16* __restrict__ BT,
    const float* __restrict__ bias0, const float* __restrict__ bias1,
    float* __restrict__ Ca, float* __restrict__ Cbf, int M, int K)
{
    __shared__ bf16 As[128 * 72];
    __shared__ bf16 Bs[64 * 72];
    const int tid  = threadIdx.x;
    const int wave = tid >> 6, lane = tid & 63;
    const int quad = lane >> 4, l16 = lane & 15;
    const int m0 = blockIdx.y * 128, n0g = blockIdx.x * 64;
    const int wm = (wave & 1) * 64, wn = (wave >> 1) * 32;
    float4v acc[4][2] = {};
    const int r  = tid >> 2;
    const int cq = (tid & 3) * 16;

    for (int k0 = 0; k0 < K; k0 += 64) {
        const bf16* sa0 = A  + (size_t)(m0 + r) * K + k0 + cq;
        const bf16* sa1 = sa0 + (size_t)64 * K;
        const bf16* sb  = BT + (size_t)(n0g + r) * K + k0 + cq;
        const float4 a00 = *(const float4*)(sa0);
        const float4 a01 = *(const float4*)(sa0 + 8);
        const float4 a10 = *(const float4*)(sa1);
        const float4 a11 = *(const float4*)(sa1 + 8);
        const float4 b0  = *(const float4*)(sb);
        const float4 b1  = *(const float4*)(sb + 8);
        __syncthreads();
        *(float4*)(&As[r * 72 + cq])            = a00;
        *(float4*)(&As[r * 72 + cq + 8])        = a01;
        *(float4*)(&As[(r + 64) * 72 + cq])     = a10;
        *(float4*)(&As[(r + 64) * 72 + cq + 8]) = a11;
        *(float4*)(&Bs[r * 72 + cq])            = b0;
        *(float4*)(&Bs[r * 72 + cq + 8])        = b1;
        __syncthreads();
        #pragma unroll
        for (int kk = 0; kk < 64; kk += 32) {
            short8 af[4], bf2[2];
            #pragma unroll
            for (int mi = 0; mi < 4; ++mi)
                af[mi] = *(const short8*)(&As[(wm + mi * 16 + l16) * 72 + kk + quad * 8]);
            #pragma unroll
            for (int ni = 0; ni < 2; ++ni)
                bf2[ni] = *(const short8*)(&Bs[(wn + ni * 16 + l16) * 72 + kk + quad * 8]);
            #pragma unroll
            for (int mi = 0; mi < 4; ++mi)
                #pragma unroll
                for (int ni = 0; ni < 2; ++ni)
                    acc[mi][ni] = __builtin_amdgcn_mfma_f32_16x16x32_bf16(
                        af[mi], bf2[ni], acc[mi][ni], 0, 0, 0);
        }
    }
    const bool loHalf = (n0g < 256);
    float* Co = loHalf ? Ca : Cbf;
    const float* bp = loHalf ? bias0 : bias1;
    const int cbase = loHalf ? n0g : (n0g - 256);
    #pragma unroll
    for (int ni = 0; ni < 2; ++ni) {
        const int col = cbase + wn + ni * 16 + l16;
        const float bv = bp[col];
        #pragma unroll
        for (int mi = 0; mi < 4; ++mi)
            #pragma unroll
            for (int rr = 0; rr < 4; ++rr) {
                const int row = m0 + wm + mi * 16 + quad * 4 + rr;
                Co[(size_t)row * 256 + col] = acc[mi][ni][rr] + bv;
            }
    }
}

// ---------------------------------------------------------------------------
// GATv2 attention, barrier-minimal: grid (NH*2, BT_G), block = (graph, head,
// i-half), 256 threads as 16x16 (ti,tj), thread tile 2 rows x 4 cols.
// ONE __syncthreads (post-staging). P/Q folded into phase 1 as register
// accumulators (same c-order as verified kernel -> bitwise identical).
// Softmax per row i: its 64 e-values live in 16 consecutive lanes (fixed ti)
// -> 4-step __shfl_xor quarter-wave reductions, no LDS. Phase 3 gets alpha
// via __shfl broadcast from the owning lane (statically unrolled).
// LDS 44.6 KB -> 3 blocks/CU. g MAY ALIAS xr (reads precede writes in-block;
// slices disjoint across blocks).
__global__ __launch_bounds__(256) void attn_kernel(
    const float* xl, const float* xr, const float* att,
    const int* msk, float* g)
{
    __shared__ float xls [64][68];   // [j][c]  (phase 3)
    __shared__ float xlsT[64][68];   // [c][j]  (phase 1)
    __shared__ float xrsT[64][36];   // [c][i]  (32 i-rows, phase 1)
    __shared__ float av[64];
    __shared__ int   ms[64];

    const int tid   = threadIdx.x;
    const int head  = blockIdx.x >> 1;
    const int half  = blockIdx.x & 1;
    const int gr    = blockIdx.y;
    const int ibase = half * 32;
    const int ti = tid >> 4, tj = tid & 15;   // 16x16 thread grid
    const int i0 = ti * 2, j0 = tj * 4;       // 2x4 tile (i half-range)

    const float* xlg = xl + (size_t)gr * NND * HID_ + head * NCH;
    const float* xrg = xr + ((size_t)gr * NND + ibase) * HID_ + head * NCH;

    // ---- staging: xl 64x64 (both layouts), xr 32x64 (transposed), att row
    {
        const int r  = tid >> 2;
        const int c0 = (tid & 3) * 16;
        const int r2 = tid >> 3;
        const int cb = (tid & 7) * 8;
        float a[4][4], b[2][4];
        #pragma unroll
        for (int k = 0; k < 4; ++k)
            *(float4*)a[k] = *(const float4*)(xlg + r * HID_ + c0 + 4 * k);
        *(float4*)b[0] = *(const float4*)(xrg + r2 * HID_ + cb);
        *(float4*)b[1] = *(const float4*)(xrg + r2 * HID_ + cb + 4);
        #pragma unroll
        for (int k = 0; k < 4; ++k)
            *(float4*)&xls[r][c0 + 4 * k] = *(float4*)a[k];
        #pragma unroll
        for (int k = 0; k < 4; ++k)
            #pragma unroll
            for (int w = 0; w < 4; ++w)
                xlsT[c0 + 4 * k + w][r] = a[k][w];
        #pragma unroll
        for (int k = 0; k < 2; ++k)
            #pragma unroll
            for (int w = 0; w < 4; ++w)
                xrsT[cb + 4 * k + w][r2] = b[k][w];
        if (tid < 64) {
            av[tid] = att[head * NCH + tid];
            ms[tid] = msk[gr * NND + tid];
        }
    }
    __syncthreads();   // the ONLY barrier

    // ---- phase 1: abs-sum + P/Q register accumulation over c
    float aa[2][4] = {};
    float p2[2] = {}, q4[4] = {};
    for (int c = 0; c < 64; ++c) {
        const float a = av[c];
        float xr2[2], xl4[4];
        *(float2*)xr2 = *(const float2*)&xrsT[c][i0];
        *(float4*)xl4 = *(const float4*)&xlsT[c][j0];
        #pragma unroll
        for (int y = 0; y < 2; ++y) p2[y] = fmaf(a, xr2[y], p2[y]);
        #pragma unroll
        for (int x = 0; x < 4; ++x) q4[x] = fmaf(a, xl4[x], q4[x]);
        #pragma unroll
        for (int y = 0; y < 2; ++y)
            #pragma unroll
            for (int x = 0; x < 4; ++x)
                aa[y][x] = fmaf(a, fabsf(xr2[y] + xl4[x]), aa[y][x]);
    }

    // ---- combine + mask + in-register softmax (16-lane group reductions)
    float inv2[2];
    {
        int mi2[2], mj4[4];
        #pragma unroll
        for (int y = 0; y < 2; ++y) mi2[y] = ms[ibase + i0 + y];
        #pragma unroll
        for (int x = 0; x < 4; ++x) mj4[x] = ms[j0 + x];
        #pragma unroll
        for (int y = 0; y < 2; ++y) {
            float e[4];
            #pragma unroll
            for (int x = 0; x < 4; ++x) {
                const float ev = fmaf(0.4f, aa[y][x], 0.6f * (p2[y] + q4[x]));
                const bool allowed = (mi2[y] && mj4[x]) || (ibase + i0 + y == j0 + x);
                e[x] = allowed ? ev : -1e9f;
            }
            float m = fmaxf(fmaxf(e[0], e[1]), fmaxf(e[2], e[3]));
            #pragma unroll
            for (int off = 1; off < 16; off <<= 1)
                m = fmaxf(m, __shfl_xor(m, off));
            float s = 0.f;
            #pragma unroll
            for (int x = 0; x < 4; ++x) {
                const float ev = __expf(e[x] - m);
                aa[y][x] = ev;          // alpha (un-normalized) stays in regs
                s += ev;
            }
            #pragma unroll
            for (int off = 1; off < 16; off <<= 1)
                s += __shfl_xor(s, off);
            inv2[y] = 1.f / s;
        }
    }

    // ---- phase 3: out[i][c] = inv[i] * sum_j alpha[i][j] * xl[j][c]
    // alpha[i][j] broadcast from owning lane ti*16+(j>>2), reg (j&3).
    {
        const int c0 = j0;            // channel tile = tj
        float oa[2][4] = {};
        for (int jb = 0; jb < 16; ++jb) {
            const int src = ti * 16 + jb;
            #pragma unroll
            for (int jj = 0; jj < 4; ++jj) {
                const int j = jb * 4 + jj;
                float xv[4];
                *(float4*)xv = *(const float4*)&xls[j][c0];
                #pragma unroll
                for (int y = 0; y < 2; ++y) {
                    const float al = __shfl(aa[y][jj], src);
                    #pragma unroll
                    for (int x = 0; x < 4; ++x)
                        oa[y][x] = fmaf(al, xv[x], oa[y][x]);
                }
            }
        }
        #pragma unroll
        for (int y = 0; y < 2; ++y) {
            const float iv = inv2[y];
            float o[4];
            #pragma unroll
            for (int x = 0; x < 4; ++x) o[x] = oa[y][x] * iv;
            float* go = g + (size_t)(gr * NND + ibase + i0 + y) * HID_ + head * NCH + c0;
            *(float4*)go = *(float4*)o;
        }
    }
}

// ---------------------------------------------------------------------------
// g + ob -> ELU -> LayerNorm -> + res -> zero unmasked.
// finalSel=0: always write hout (+ optional bf16 mirror hb).
// finalSel=1: hout = d_out holding h0; only overwrite keep-graphs.
__global__ __launch_bounds__(256) void epilogue_kernel(
    const float* __restrict__ g, const float* res,
    const float* __restrict__ ob, const float* __restrict__ lns,
    const float* __restrict__ lnb, const int* __restrict__ msk,
    float* hout, bf16* hb, int finalSel)
{
    const int lane = threadIdx.x & 63;
    const int wave = threadIdx.x >> 6;
    const int m = blockIdx.x * 4 + wave;
    if (finalSel) {
        const int gr = m >> 6;
        const int mv = msk[gr * NND + lane];
        const unsigned long long bal = __ballot(mv != 0);
        if (__popcll(bal) <= 1) return;   // leave h0 rows in d_out
    }
    const float* grow = g + (size_t)m * HID_;
    float v[4];
    float sum = 0.f;
    #pragma unroll
    for (int q = 0; q < 4; ++q) {
        const int c = q * 64 + lane;
        float x = grow[c] + ob[c];
        x = x > 0.f ? x : (__expf(x) - 1.f);   // ELU (alpha=1)
        v[q] = x; sum += x;
    }
    #pragma unroll
    for (int off = 1; off < 64; off <<= 1) sum += __shfl_xor(sum, off);
    const float mu = sum * (1.f / 256.f);
    float vs = 0.f;
    #pragma unroll
    for (int q = 0; q < 4; ++q) { const float d = v[q] - mu; vs += d * d; }
    #pragma unroll
    for (int off = 1; off < 64; off <<= 1) vs += __shfl_xor(vs, off);
    const float rstd = rsqrtf(vs * (1.f / 256.f) + LN_EPS_);
    const int mnode = msk[m];
    const float* rrow = res + (size_t)m * HID_;
    float* ho = hout + (size_t)m * HID_;
    #pragma unroll
    for (int q = 0; q < 4; ++q) {
        const int c = q * 64 + lane;
        float y = (v[q] - mu) * rstd * lns[c] + lnb[c];
        y += rrow[c];
        y = mnode ? y : 0.f;
        ho[c] = y;
        if (hb) hb[(size_t)m * HID_ + c] = __float2bfloat16(y);
    }
}

// ---------------------------------------------------------------------------
extern "C" void kernel_launch(void* const* d_in, const int* in_sizes, int n_in,
                              void* d_out, int out_size, void* d_ws, size_t ws_size,
                              hipStream_t stream) {
    const float* x    = (const float*)d_in[0];
    const float* W_in = (const float*)d_in[2];
    const float* b_in = (const float*)d_in[3];
    const float* Wl   = (const float*)d_in[4];
    const float* bl   = (const float*)d_in[5];
    const float* Wr   = (const float*)d_in[6];
    const float* br   = (const float*)d_in[7];
    const float* att  = (const float*)d_in[8];
    const float* ob   = (const float*)d_in[9];
    const float* lns  = (const float*)d_in[10];
    const float* lnb  = (const float*)d_in[11];
    float* out = (float*)d_out;

    // ws (~29 MB): [mcan 32K][h 8M][xlb 8M][xra 8M][hxb 4M][WlrT 512K]
    char* w = (char*)d_ws;
    int*   mcan = (int*)w;                      w += 32768;
    float* h    = (float*)w;                    w += (size_t)NROWS * HID_ * 4;
    float* xlb  = (float*)w;                    w += (size_t)NROWS * HID_ * 4;
    float* xra  = (float*)w;                    w += (size_t)NROWS * HID_ * 4;
    bf16*  hxb  = (bf16*)w;                     w += (size_t)NROWS * HID_ * 2;
    bf16*  WlrT = (bf16*)w;                     // [L][512][256]

    // D1: input GEMM + Wl/Wr transposes + mask canon (heterogeneous blocks)
    prep_gemm_in_kernel<<<769, 256, 0, stream>>>(
        x, (const unsigned*)d_in[1], W_in, b_in, Wl, Wr, out, hxb, WlrT, mcan);

    // D2: layer-0 xl|xr GEMM
    gemm_mfma_kernel<<<dim3(512 / 64, NROWS / 128), 256, 0, stream>>>(
        hxb, WlrT, bl, br, xlb, xra, NROWS, HID_);

    // D3: layer-0 attention (g aliases xra)
    attn_kernel<<<dim3(NH * 2, BT_G), 256, 0, stream>>>(
        xlb, xra, att, mcan, xra);

    // D4: layer-0 epilogue (writes fp32 h + bf16 hxb)
    epilogue_kernel<<<NROWS / 4, 256, 0, stream>>>(
        xra, out, ob, lns, lnb, mcan, h, hxb, 0);

    // D5: layer-1 xl|xr GEMM
    gemm_mfma_kernel<<<dim3(512 / 64, NROWS / 128), 256, 0, stream>>>(
        hxb, WlrT + (size_t)512 * HID_, bl + HID_, br + HID_, xlb, xra, NROWS, HID_);

    // D6: layer-1 attention (g aliases xra)
    attn_kernel<<<dim3(NH * 2, BT_G), 256, 0, stream>>>(
        xlb, xra, att + NH * NCH, mcan, xra);

    // D7: final epilogue with keep-graph select
    epilogue_kernel<<<NROWS / 4, 256, 0, stream>>>(
        xra, h, ob + HID_, lns + HID_, lnb + HID_, mcan,
        out, (bf16*)nullptr, 1);

    (void)in_sizes; (void)n_in; (void)out_size; (void)ws_size;
}

// Round 8
// 169.020 us; speedup vs baseline: 4.0743x; 1.0440x over previous
//
#include <hip/hip_runtime.h>
#include <hip/hip_bf16.h>

// Problem constants (B=2,T=64,N=64,D_IN=512,HID=256,L=2,H=4,C=64)
#define BT_G   128
#define NND    64
#define D_IN_  512
#define HID_   256
#define NH     4
#define NCH    64
#define NROWS  8192
#define LN_EPS_    1e-5f

typedef __hip_bfloat16 bf16;
typedef __attribute__((ext_vector_type(8))) short short8;   // 8 bf16 = 4 VGPRs
typedef __attribute__((ext_vector_type(4))) float float4v;  // MFMA C/D

// ---------------------------------------------------------------------------
// Dispatch 1 (heterogeneous, 769 blocks):
//   bid <  512 : input GEMM h0 = x @ W_in^T + b_in (64x64 tile, BK=64),
//                transposing W_in tiles in-staging (no WTin buffer).
//   bid <  768 : Wl/Wr -> WlrT transposes (consumed by later dispatches).
//   bid == 768 : mask canonicalize -> mcan.
union PrepArena {
    float t[32][33];
    struct { bf16 As[64 * 72]; bf16 Bs[64 * 72]; } g;
    int flags[4];
};

__global__ __launch_bounds__(256) void prep_gemm_in_kernel(
    const float* __restrict__ x, const unsigned* __restrict__ mw,
    const float* __restrict__ W_in, const float* __restrict__ b_in,
    const float* __restrict__ Wl, const float* __restrict__ Wr,
    float* __restrict__ Cf, bf16* __restrict__ Cb16,
    bf16* __restrict__ WlrT, int* __restrict__ mout)
{
    __shared__ PrepArena ar;
    const int tid = threadIdx.x;
    const int bid = blockIdx.x;

    if (bid < 512) {
        bf16* As = ar.g.As;
        bf16* Bs = ar.g.Bs;
        const int wave = tid >> 6, lane = tid & 63;
        const int quad = lane >> 4, l16 = lane & 15;
        const int m0 = (bid >> 2) * 64, n0 = (bid & 3) * 64;
        const int wm = (wave & 1) * 32, wn = (wave >> 1) * 32;
        float4v acc[2][2] = {};
        const int r  = tid >> 2;
        const int cq = (tid & 3) * 16;
        for (int k0 = 0; k0 < D_IN_; k0 += 64) {
            const float* sa = x + (size_t)(m0 + r) * D_IN_ + k0 + cq;
            const float4 f0 = *(const float4*)(sa);
            const float4 f1 = *(const float4*)(sa + 4);
            const float4 f2 = *(const float4*)(sa + 8);
            const float4 f3 = *(const float4*)(sa + 12);
            // B-tile: Bs[n][k] = bf16(W_in[k0+k][n0+n]); read rows, scatter.
            const float* sw = W_in + (size_t)(k0 + r) * HID_ + n0 + cq;
            float wv[16];
            *(float4*)(wv)      = *(const float4*)(sw);
            *(float4*)(wv + 4)  = *(const float4*)(sw + 4);
            *(float4*)(wv + 8)  = *(const float4*)(sw + 8);
            *(float4*)(wv + 12) = *(const float4*)(sw + 12);
            union { bf16 hh[16]; float4 v[2]; } u;
            u.hh[0]=__float2bfloat16(f0.x); u.hh[1]=__float2bfloat16(f0.y);
            u.hh[2]=__float2bfloat16(f0.z); u.hh[3]=__float2bfloat16(f0.w);
            u.hh[4]=__float2bfloat16(f1.x); u.hh[5]=__float2bfloat16(f1.y);
            u.hh[6]=__float2bfloat16(f1.z); u.hh[7]=__float2bfloat16(f1.w);
            u.hh[8]=__float2bfloat16(f2.x); u.hh[9]=__float2bfloat16(f2.y);
            u.hh[10]=__float2bfloat16(f2.z); u.hh[11]=__float2bfloat16(f2.w);
            u.hh[12]=__float2bfloat16(f3.x); u.hh[13]=__float2bfloat16(f3.y);
            u.hh[14]=__float2bfloat16(f3.z); u.hh[15]=__float2bfloat16(f3.w);
            __syncthreads();
            *(float4*)(&As[r * 72 + cq])     = u.v[0];
            *(float4*)(&As[r * 72 + cq + 8]) = u.v[1];
            #pragma unroll
            for (int j = 0; j < 16; ++j)
                Bs[(cq + j) * 72 + r] = __float2bfloat16(wv[j]);
            __syncthreads();
            #pragma unroll
            for (int kk = 0; kk < 64; kk += 32) {
                short8 af[2], bf2[2];
                #pragma unroll
                for (int mi = 0; mi < 2; ++mi)
                    af[mi] = *(const short8*)(&As[(wm + mi * 16 + l16) * 72 + kk + quad * 8]);
                #pragma unroll
                for (int ni = 0; ni < 2; ++ni)
                    bf2[ni] = *(const short8*)(&Bs[(wn + ni * 16 + l16) * 72 + kk + quad * 8]);
                #pragma unroll
                for (int mi = 0; mi < 2; ++mi)
                    #pragma unroll
                    for (int ni = 0; ni < 2; ++ni)
                        acc[mi][ni] = __builtin_amdgcn_mfma_f32_16x16x32_bf16(
                            af[mi], bf2[ni], acc[mi][ni], 0, 0, 0);
            }
        }
        #pragma unroll
        for (int ni = 0; ni < 2; ++ni) {
            const int col = n0 + wn + ni * 16 + l16;
            const float bv = b_in[col];
            #pragma unroll
            for (int mi = 0; mi < 2; ++mi)
                #pragma unroll
                for (int rr = 0; rr < 4; ++rr) {
                    const int row = m0 + wm + mi * 16 + quad * 4 + rr;
                    const float v = acc[mi][ni][rr] + bv;
                    Cf[(size_t)row * HID_ + col] = v;
                    Cb16[(size_t)row * HID_ + col] = __float2bfloat16(v);
                }
        }
    } else if (bid < 768) {
        const int q = bid - 512;
        const int z4 = q >> 6;                 // 0,1: Wl li ; 2,3: Wr li
        const int s = q & 63;
        const int n0 = (s & 7) * 32, k0 = (s >> 3) * 32;
        const float* src = (z4 < 2) ? (Wl + z4 * 65536) : (Wr + (z4 - 2) * 65536);
        bf16* dst = WlrT + ((z4 < 2) ? (size_t)z4 * 131072
                                     : (size_t)(z4 - 2) * 131072 + 65536);
        const int tx = tid & 31, ty = tid >> 5;
        #pragma unroll
        for (int i = 0; i < 4; ++i)
            ar.t[ty + 8 * i][tx] = src[(size_t)(k0 + ty + 8 * i) * 256 + n0 + tx];
        __syncthreads();
        #pragma unroll
        for (int i = 0; i < 4; ++i)
            dst[(size_t)(n0 + ty + 8 * i) * 256 + k0 + tx] =
                __float2bfloat16(ar.t[tx][ty + 8 * i]);
    } else {
        int* fl = ar.flags;
        if (tid == 0) { fl[0] = 1; fl[1] = 1; fl[2] = 1; fl[3] = 1; }
        __syncthreads();
        int aI = 1, aF = 1, aB = 1, aC = 1;
        for (int i = tid; i < 2048; i += 256) {   // 8 KB probe — safe all layouts
            const unsigned w2 = mw[i];
            aI &= (w2 <= 1u);
            aF &= (w2 == 0u || w2 == 0x3F800000u);
            const unsigned lo = w2 & 0xFFFFu, hi = w2 >> 16;
            aB &= ((lo == 0u || lo == 0x3F80u) && (hi == 0u || hi == 0x3F80u));
            aC &= (((w2 | (w2 >> 8) | (w2 >> 16) | (w2 >> 24)) & 0xFEu) == 0u);
        }
        if (!aI) atomicAnd(&fl[0], 0);
        if (!aF) atomicAnd(&fl[1], 0);
        if (!aB) atomicAnd(&fl[2], 0);
        if (!aC) atomicAnd(&fl[3], 0);
        __syncthreads();
        const int layout = (fl[0] || fl[1]) ? 0 : (fl[2] ? 2 : (fl[3] ? 3 : 0));
        for (int i = tid; i < NROWS; i += 256) {
            int v;
            if (layout == 2)      v = (((const unsigned short*)mw)[i] != 0);
            else if (layout == 3) v = (((const unsigned char*)mw)[i] != 0);
            else                  v = (mw[i] != 0u);
            mout[i] = v;
        }
    }
}

// ---------------------------------------------------------------------------
// Fused xl|xr GEMM + GATv2 attention per (head, graph): 512 blocks.
// GEMM: 64 rows (one graph) x 128 cols (xl head-cols | xr head-cols), K=256,
// accumulated in registers with the exact gemm_mfma k-order. acc + bias is
// scattered straight into the attention LDS layouts (xls/xlsT/xrsT) — xl/xr
// never touch global memory. Then the r7-verified register-softmax attention
// (one barrier) computes g for this (graph, head).
// C-fragment mapping (verified since round 0): row=wm+mi*16+quad*4+rr,
// col=wn+ni*16+l16. Waves 0,1 (wn=0) own xl cols; waves 2,3 (wn=64) own xr.
union FusedArena {
    struct { bf16 As[64 * 72]; bf16 Bs[128 * 72]; } g;      // 27.6 KB
    struct { float xls[64][68], xlsT[64][68], xrsT[64][68]; } a;  // 52.2 KB
};

__global__ __launch_bounds__(256) void gemm_attn_kernel(
    const bf16* __restrict__ hxbA, const bf16* __restrict__ WlrTl,
    const float* __restrict__ bll, const float* __restrict__ brl,
    const float* __restrict__ attl, const int* __restrict__ msk,
    float* __restrict__ g)
{
    __shared__ FusedArena ar;
    __shared__ float av[64];
    __shared__ int   ms[64];

    const int tid  = threadIdx.x;
    const int head = blockIdx.x, gr = blockIdx.y;
    const int wave = tid >> 6, lane = tid & 63;
    const int quad = lane >> 4, l16 = lane & 15;
    const int wm = (wave & 1) * 32;        // row offset (graph node)
    const int wn = (wave >> 1) * 64;       // col offset: 0 = xl, 64 = xr
    float4v acc[2][4] = {};

    // ---- GEMM: C[64][128] = hxb[gr rows][256] @ B^T + bias ---------------
    {
        bf16* As = ar.g.As;
        bf16* Bs = ar.g.Bs;
        const int rA  = tid >> 2;            // 0..63
        const int cqA = (tid & 3) * 16;
        const int rB  = tid >> 1;            // 0..127
        const int cqB = (tid & 1) * 32;
        // B-panel source row in WlrT: xl j<64 -> head*64+j ; xr -> 256+head*64+j
        const int srcB = (rB < 64) ? (head * NCH + rB) : (256 + head * NCH + rB - 64);
        for (int k0 = 0; k0 < HID_; k0 += 64) {
            const bf16* sa = hxbA + (size_t)(gr * NND + rA) * HID_ + k0 + cqA;
            const float4 a0 = *(const float4*)(sa);
            const float4 a1 = *(const float4*)(sa + 8);
            const bf16* sb = WlrTl + (size_t)srcB * HID_ + k0 + cqB;
            const float4 b0 = *(const float4*)(sb);
            const float4 b1 = *(const float4*)(sb + 8);
            const float4 b2 = *(const float4*)(sb + 16);
            const float4 b3 = *(const float4*)(sb + 24);
            __syncthreads();
            *(float4*)(&As[rA * 72 + cqA])      = a0;
            *(float4*)(&As[rA * 72 + cqA + 8])  = a1;
            *(float4*)(&Bs[rB * 72 + cqB])      = b0;
            *(float4*)(&Bs[rB * 72 + cqB + 8])  = b1;
            *(float4*)(&Bs[rB * 72 + cqB + 16]) = b2;
            *(float4*)(&Bs[rB * 72 + cqB + 24]) = b3;
            __syncthreads();
            #pragma unroll
            for (int kk = 0; kk < 64; kk += 32) {
                short8 af[2], bf2[4];
                #pragma unroll
                for (int mi = 0; mi < 2; ++mi)
                    af[mi] = *(const short8*)(&As[(wm + mi * 16 + l16) * 72 + kk + quad * 8]);
                #pragma unroll
                for (int ni = 0; ni < 4; ++ni)
                    bf2[ni] = *(const short8*)(&Bs[(wn + ni * 16 + l16) * 72 + kk + quad * 8]);
                #pragma unroll
                for (int mi = 0; mi < 2; ++mi)
                    #pragma unroll
                    for (int ni = 0; ni < 4; ++ni)
                        acc[mi][ni] = __builtin_amdgcn_mfma_f32_16x16x32_bf16(
                            af[mi], bf2[ni], acc[mi][ni], 0, 0, 0);
            }
        }
    }
    __syncthreads();   // all As/Bs reads done before arena reuse

    // ---- scatter acc (+bias) into attention layouts ----------------------
    {
        const bool xlW = (wn == 0);
        const float* bp = xlW ? bll : brl;
        float bias[4];
        #pragma unroll
        for (int ni = 0; ni < 4; ++ni)
            bias[ni] = bp[head * NCH + ni * 16 + l16];
        #pragma unroll
        for (int mi = 0; mi < 2; ++mi)
            #pragma unroll
            for (int ni = 0; ni < 4; ++ni)
                #pragma unroll
                for (int rr = 0; rr < 4; ++rr) {
                    const int row = wm + mi * 16 + quad * 4 + rr;   // node
                    const int c   = ni * 16 + l16;                  // channel
                    const float v = acc[mi][ni][rr] + bias[ni];
                    if (xlW) {
                        ar.a.xls[row][c] = v;
                        ar.a.xlsT[c][row] = v;
                    } else {
                        ar.a.xrsT[c][row] = v;
                    }
                }
        if (tid < 64) {
            av[tid] = attl[head * NCH + tid];
            ms[tid] = msk[gr * NND + tid];
        }
    }
    __syncthreads();   // the only attention barrier

    // ---- phase 1: abs-sum + P/Q register accumulation (r7-verified) ------
    const int ti = tid >> 4, tj = tid & 15;   // 16x16 thread grid
    const int i0 = ti * 4, j0 = tj * 4;       // 4x4 tile
    float aa[4][4] = {};
    float p4[4] = {}, q4[4] = {};
    for (int c = 0; c < 64; ++c) {
        const float a = av[c];
        float xr4[4], xl4[4];
        *(float4*)xr4 = *(const float4*)&ar.a.xrsT[c][i0];
        *(float4*)xl4 = *(const float4*)&ar.a.xlsT[c][j0];
        #pragma unroll
        for (int y = 0; y < 4; ++y) p4[y] = fmaf(a, xr4[y], p4[y]);
        #pragma unroll
        for (int x = 0; x < 4; ++x) q4[x] = fmaf(a, xl4[x], q4[x]);
        #pragma unroll
        for (int y = 0; y < 4; ++y)
            #pragma unroll
            for (int x = 0; x < 4; ++x)
                aa[y][x] = fmaf(a, fabsf(xr4[y] + xl4[x]), aa[y][x]);
    }

    // ---- combine + mask + register softmax (16-lane group reductions) ----
    float inv4[4];
    {
        int mi4[4], mj4[4];
        #pragma unroll
        for (int y = 0; y < 4; ++y) mi4[y] = ms[i0 + y];
        #pragma unroll
        for (int x = 0; x < 4; ++x) mj4[x] = ms[j0 + x];
        #pragma unroll
        for (int y = 0; y < 4; ++y) {
            float e[4];
            #pragma unroll
            for (int x = 0; x < 4; ++x) {
                const float ev = fmaf(0.4f, aa[y][x], 0.6f * (p4[y] + q4[x]));
                const bool allowed = (mi4[y] && mj4[x]) || (i0 + y == j0 + x);
                e[x] = allowed ? ev : -1e9f;
            }
            float m = fmaxf(fmaxf(e[0], e[1]), fmaxf(e[2], e[3]));
            #pragma unroll
            for (int off = 1; off < 16; off <<= 1)
                m = fmaxf(m, __shfl_xor(m, off));
            float s = 0.f;
            #pragma unroll
            for (int x = 0; x < 4; ++x) {
                const float ev = __expf(e[x] - m);
                aa[y][x] = ev;            // unnormalized alpha stays in regs
                s += ev;
            }
            #pragma unroll
            for (int off = 1; off < 16; off <<= 1)
                s += __shfl_xor(s, off);
            inv4[y] = 1.f / s;
        }
    }

    // ---- phase 3: g[i][head*64+c] = inv[i] * sum_j alpha[i][j]*xl[j][c] --
    {
        const int c0 = j0;                // channel tile = tj
        float oa[4][4] = {};
        for (int jb = 0; jb < 16; ++jb) {
            const int src = ti * 16 + jb; // wave-local (&63 implicit)
            #pragma unroll
            for (int jj = 0; jj < 4; ++jj) {
                const int j = jb * 4 + jj;
                float xv[4];
                *(float4*)xv = *(const float4*)&ar.a.xls[j][c0];
                #pragma unroll
                for (int y = 0; y < 4; ++y) {
                    const float al = __shfl(aa[y][jj], src);
                    #pragma unroll
                    for (int x = 0; x < 4; ++x)
                        oa[y][x] = fmaf(al, xv[x], oa[y][x]);
                }
            }
        }
        #pragma unroll
        for (int y = 0; y < 4; ++y) {
            const float iv = inv4[y];
            float o[4];
            #pragma unroll
            for (int x = 0; x < 4; ++x) o[x] = oa[y][x] * iv;
            float* go = g + (size_t)(gr * NND + i0 + y) * HID_ + head * NCH + c0;
            *(float4*)go = *(float4*)o;
        }
    }
}

// ---------------------------------------------------------------------------
// g + ob -> ELU -> LayerNorm -> + res -> zero unmasked.
// finalSel=0: always write hout (+ optional bf16 mirror hb).
// finalSel=1: hout = d_out holding h0; only overwrite keep-graphs.
__global__ __launch_bounds__(256) void epilogue_kernel(
    const float* __restrict__ g, const float* res,
    const float* __restrict__ ob, const float* __restrict__ lns,
    const float* __restrict__ lnb, const int* __restrict__ msk,
    float* hout, bf16* hb, int finalSel)
{
    const int lane = threadIdx.x & 63;
    const int wave = threadIdx.x >> 6;
    const int m = blockIdx.x * 4 + wave;
    if (finalSel) {
        const int gr = m >> 6;
        const int mv = msk[gr * NND + lane];
        const unsigned long long bal = __ballot(mv != 0);
        if (__popcll(bal) <= 1) return;   // leave h0 rows in d_out
    }
    const float* grow = g + (size_t)m * HID_;
    float v[4];
    float sum = 0.f;
    #pragma unroll
    for (int q = 0; q < 4; ++q) {
        const int c = q * 64 + lane;
        float x = grow[c] + ob[c];
        x = x > 0.f ? x : (__expf(x) - 1.f);   // ELU (alpha=1)
        v[q] = x; sum += x;
    }
    #pragma unroll
    for (int off = 1; off < 64; off <<= 1) sum += __shfl_xor(sum, off);
    const float mu = sum * (1.f / 256.f);
    float vs = 0.f;
    #pragma unroll
    for (int q = 0; q < 4; ++q) { const float d = v[q] - mu; vs += d * d; }
    #pragma unroll
    for (int off = 1; off < 64; off <<= 1) vs += __shfl_xor(vs, off);
    const float rstd = rsqrtf(vs * (1.f / 256.f) + LN_EPS_);
    const int mnode = msk[m];
    const float* rrow = res + (size_t)m * HID_;
    float* ho = hout + (size_t)m * HID_;
    #pragma unroll
    for (int q = 0; q < 4; ++q) {
        const int c = q * 64 + lane;
        float y = (v[q] - mu) * rstd * lns[c] + lnb[c];
        y += rrow[c];
        y = mnode ? y : 0.f;
        ho[c] = y;
        if (hb) hb[(size_t)m * HID_ + c] = __float2bfloat16(y);
    }
}

// ---------------------------------------------------------------------------
extern "C" void kernel_launch(void* const* d_in, const int* in_sizes, int n_in,
                              void* d_out, int out_size, void* d_ws, size_t ws_size,
                              hipStream_t stream) {
    const float* x    = (const float*)d_in[0];
    const float* W_in = (const float*)d_in[2];
    const float* b_in = (const float*)d_in[3];
    const float* Wl   = (const float*)d_in[4];
    const float* bl   = (const float*)d_in[5];
    const float* Wr   = (const float*)d_in[6];
    const float* br   = (const float*)d_in[7];
    const float* att  = (const float*)d_in[8];
    const float* ob   = (const float*)d_in[9];
    const float* lns  = (const float*)d_in[10];
    const float* lnb  = (const float*)d_in[11];
    float* out = (float*)d_out;

    // ws (~21 MB): [mcan 32K][h 8M][gbuf 8M][hxb 4M][WlrT 512K]
    char* w = (char*)d_ws;
    int*   mcan = (int*)w;                      w += 32768;
    float* h    = (float*)w;                    w += (size_t)NROWS * HID_ * 4;
    float* gbuf = (float*)w;                    w += (size_t)NROWS * HID_ * 4;
    bf16*  hxb  = (bf16*)w;                     w += (size_t)NROWS * HID_ * 2;
    bf16*  WlrT = (bf16*)w;                     // [L][512][256]

    // D1: input GEMM + Wl/Wr transposes + mask canon (heterogeneous blocks)
    prep_gemm_in_kernel<<<769, 256, 0, stream>>>(
        x, (const unsigned*)d_in[1], W_in, b_in, Wl, Wr, out, hxb, WlrT, mcan);

    // D2: layer-0 fused GEMM+attention (xl/xr stay on-chip)
    gemm_attn_kernel<<<dim3(NH, BT_G), 256, 0, stream>>>(
        hxb, WlrT, bl, br, att, mcan, gbuf);

    // D3: layer-0 epilogue (writes fp32 h + bf16 hxb)
    epilogue_kernel<<<NROWS / 4, 256, 0, stream>>>(
        gbuf, out, ob, lns, lnb, mcan, h, hxb, 0);

    // D4: layer-1 fused GEMM+attention
    gemm_attn_kernel<<<dim3(NH, BT_G), 256, 0, stream>>>(
        hxb, WlrT + (size_t)512 * HID_, bl + HID_, br + HID_,
        att + NH * NCH, mcan, gbuf);

    // D5: final epilogue with keep-graph select
    epilogue_kernel<<<NROWS / 4, 256, 0, stream>>>(
        gbuf, h, ob + HID_, lns + HID_, lnb + HID_, mcan,
        out, (bf16*)nullptr, 1);

    (void)in_sizes; (void)n_in; (void)out_size; (void)ws_size;
}